// Round 1
// baseline (232.088 us; speedup 1.0000x reference)
//
#include <hip/hip_runtime.h>

// Conv2d 3x3 s1 p1 as implicit GEMM, bf16 MFMA, fp32 accumulate.
// N=32, Cin=128, H=W=56, Cout=256. M=100352, K=1152 (kh,kw outer / ci inner).

#define NB   32
#define CIN  128
#define HH   56
#define WWD  56
#define COUT 256
#define HWP  3136      // 56*56
#define KTOT 1152      // 9*128
#define MTOT 100352    // 32*3136

typedef __bf16 bf16x8 __attribute__((ext_vector_type(8)));
typedef float  f32x4  __attribute__((ext_vector_type(4)));
typedef unsigned short u16;

__device__ __forceinline__ u16 f2b(float f) {
  // RNE float -> bf16 (inputs finite)
  unsigned u = __float_as_uint(f);
  u += 0x7fffu + ((u >> 16) & 1u);
  return (u16)(u >> 16);
}

__device__ __forceinline__ void load_lds16(const void* g, void* l) {
  __builtin_amdgcn_global_load_lds(
      (const __attribute__((address_space(1))) unsigned int*)g,
      (__attribute__((address_space(3))) unsigned int*)l, 16, 0, 0);
}

// x: [32][128][3136] f32  ->  xt: [32][3136][128] bf16  (NCHW -> NHWC + cvt)
__global__ __launch_bounds__(256) void k_transpose_x(const float* __restrict__ x,
                                                     u16* __restrict__ xt) {
  __shared__ float tile[32][33];
  const int n  = blockIdx.z;
  const int p0 = blockIdx.x * 32;
  const int c0 = blockIdx.y * 32;
  const int tx = threadIdx.x;   // 0..31
  const int ty = threadIdx.y;   // 0..7
  const float* xp = x + (size_t)n * CIN * HWP;
#pragma unroll
  for (int j = 0; j < 4; ++j) {
    int c = c0 + ty + j * 8;
    tile[ty + j * 8][tx] = xp[(size_t)c * HWP + p0 + tx];
  }
  __syncthreads();
  u16* xo = xt + (size_t)n * HWP * CIN;
#pragma unroll
  for (int j = 0; j < 4; ++j) {
    int p = p0 + ty + j * 8;
    xo[(size_t)p * CIN + c0 + tx] = f2b(tile[tx][ty + j * 8]);
  }
}

// w: [256][128][3][3] f32 -> Wt: [256][1152] bf16 with k = (kh*3+kw)*128 + ci
// Also zero the 128-element bf16 pad page zb.
__global__ __launch_bounds__(256) void k_transform_w(const float* __restrict__ w,
                                                     u16* __restrict__ Wt,
                                                     u16* __restrict__ zb) {
  int o = blockIdx.x * 256 + threadIdx.x;
  if (o < COUT * KTOT) {
    int co  = o / KTOT;
    int rem = o - co * KTOT;
    int kk  = rem >> 7;      // (kh*3+kw)
    int ci  = rem & 127;
    int kh  = kk / 3;
    int kw  = kk - kh * 3;
    Wt[o] = f2b(w[(((size_t)co * CIN + ci) * 3 + kh) * 3 + kw]);
  }
  if (blockIdx.x == 0 && threadIdx.x < 128) zb[threadIdx.x] = 0;
}

// Implicit-GEMM conv. Grid (784, 2), block 256 (4 waves).
// D[co][m] = sum_k Wt[co][k] * im2col[k][m];  128x128 tile, BK=32, 36 K-iters.
__global__ __launch_bounds__(256, 3) void k_conv_gemm(
    const u16* __restrict__ xt, const u16* __restrict__ Wt,
    const u16* __restrict__ zb, const float* __restrict__ bias,
    float* __restrict__ out) {
  __shared__ u16 lW[128 * 32];
  __shared__ u16 lX[128 * 32];

  const int tid  = threadIdx.x;
  const int wave = tid >> 6;
  const int lane = tid & 63;
  const int m0   = blockIdx.x * 128;
  const int co0  = blockIdx.y * 128;

  const int wrow = (wave >> 1) * 64;   // co offset of this wave's 64x64
  const int wcol = (wave & 1) * 64;    // m offset

  // global_load_lds lane mapping: lane l -> row = chunk*16 + l/4, 16B piece (l&3)
  const int koff8 = (lane & 3) * 8;    // element offset within a 32-elem k-row
  const int rsub  = lane >> 2;         // 0..15

  int soh[2], sow[2], sbase[2];
#pragma unroll
  for (int t = 0; t < 2; ++t) {
    int chunk = wave * 2 + t;
    int m = m0 + chunk * 16 + rsub;
    int n = m / HWP;
    int s = m - n * HWP;
    int oh = s / WWD;
    int ow = s - oh * WWD;
    soh[t] = oh; sow[t] = ow;
    sbase[t] = n * HWP + oh * WWD + ow;   // pixel index into xt
  }

  f32x4 acc[4][4];
#pragma unroll
  for (int i = 0; i < 4; ++i)
#pragma unroll
    for (int j = 0; j < 4; ++j) acc[i][j] = (f32x4){0.f, 0.f, 0.f, 0.f};

  const int r = lane & 15;
  const int q = lane >> 4;

  for (int kt = 0; kt < 36; ++kt) {
    const int ksp = kt >> 2;              // 0..8 = kh*3+kw
    const int kh  = ksp / 3;
    const int kw  = ksp - kh * 3;
    const int ci0 = (kt & 3) << 5;
    const int kg  = kt << 5;

    __syncthreads();   // all waves done reading LDS from previous iter
#pragma unroll
    for (int t = 0; t < 2; ++t) {         // stage W tile (8 KB)
      int chunk = wave * 2 + t;
      const u16* g = Wt + (size_t)(co0 + chunk * 16 + rsub) * KTOT + kg + koff8;
      load_lds16(g, &lW[chunk * 512]);
    }
#pragma unroll
    for (int t = 0; t < 2; ++t) {         // stage X tile (8 KB), halo -> zero page
      int chunk = wave * 2 + t;
      int ih = soh[t] + kh - 1;
      int iw = sow[t] + kw - 1;
      bool valid = ((unsigned)ih < HH) && ((unsigned)iw < WWD);
      const u16* g = valid
          ? xt + (size_t)(sbase[t] + (kh - 1) * WWD + (kw - 1)) * CIN + ci0 + koff8
          : zb + koff8;
      load_lds16(g, &lX[chunk * 512]);
    }
    __syncthreads();   // drains vmcnt(0): staged data visible

    bf16x8 a[4], b[4];
#pragma unroll
    for (int ti = 0; ti < 4; ++ti)
      a[ti] = *(const bf16x8*)(&lW[(wrow + ti * 16 + r) * 32 + q * 8]);
#pragma unroll
    for (int tj = 0; tj < 4; ++tj)
      b[tj] = *(const bf16x8*)(&lX[(wcol + tj * 16 + r) * 32 + q * 8]);
#pragma unroll
    for (int ti = 0; ti < 4; ++ti)
#pragma unroll
      for (int tj = 0; tj < 4; ++tj)
        acc[ti][tj] =
            __builtin_amdgcn_mfma_f32_16x16x32_bf16(a[ti], b[tj], acc[ti][tj], 0, 0, 0);
  }

  // Epilogue: C/D layout col=lane&15 (m), row=q*4+reg (co). Add bias, store f32.
#pragma unroll
  for (int tj = 0; tj < 4; ++tj) {
    int m = m0 + wcol + tj * 16 + r;
    int n = m / HWP;
    int s = m - n * HWP;
#pragma unroll
    for (int ti = 0; ti < 4; ++ti) {
      f32x4 v = acc[ti][tj];
#pragma unroll
      for (int e = 0; e < 4; ++e) {
        int co = co0 + wrow + ti * 16 + q * 4 + e;
        out[((size_t)n * COUT + co) * HWP + s] = v[e] + bias[co];
      }
    }
  }
}

extern "C" void kernel_launch(void* const* d_in, const int* in_sizes, int n_in,
                              void* d_out, int out_size, void* d_ws, size_t ws_size,
                              hipStream_t stream) {
  const float* x    = (const float*)d_in[0];
  const float* w    = (const float*)d_in[1];
  const float* bias = (const float*)d_in[2];
  float* out        = (float*)d_out;

  u16* xt = (u16*)d_ws;                       // 12,845,056 bf16 = 25.7 MB
  u16* Wt = xt + (size_t)NB * HWP * CIN;      // 294,912 bf16
  u16* zb = Wt + (size_t)COUT * KTOT;         // 128 bf16 zero page

  k_transpose_x<<<dim3(98, 4, 32), dim3(32, 8), 0, stream>>>(x, xt);
  k_transform_w<<<dim3(1152), dim3(256), 0, stream>>>(w, Wt, zb);
  k_conv_gemm<<<dim3(784, 2), dim3(256), 0, stream>>>(xt, Wt, zb, bias, out);
}

// Round 2
// 207.593 us; speedup vs baseline: 1.1180x; 1.1180x over previous
//
#include <hip/hip_runtime.h>

// Conv2d 3x3 s1 p1 as implicit GEMM, bf16 MFMA, fp32 accumulate.
// N=32, Cin=128, H=W=56, Cout=256. M=100352, K=1152 (kh,kw outer / ci inner).
// R2: vectorized transpose; GEMM BK=64, XOR LDS piece-swizzle, launch_bounds(256,4).

#define NB   32
#define CIN  128
#define HH   56
#define WWD  56
#define COUT 256
#define HWP  3136      // 56*56
#define KTOT 1152      // 9*128
#define MTOT 100352    // 32*3136

typedef __bf16 bf16x8 __attribute__((ext_vector_type(8)));
typedef float  f32x4  __attribute__((ext_vector_type(4)));
typedef unsigned short u16;
typedef u16 u16x4 __attribute__((ext_vector_type(4)));
typedef u16 u16x8 __attribute__((ext_vector_type(8)));

__device__ __forceinline__ u16 f2b(float f) {
  unsigned u = __float_as_uint(f);
  u += 0x7fffu + ((u >> 16) & 1u);
  return (u16)(u >> 16);
}

__device__ __forceinline__ void load_lds16(const void* g, void* l) {
  __builtin_amdgcn_global_load_lds(
      (const __attribute__((address_space(1))) unsigned int*)g,
      (__attribute__((address_space(3))) unsigned int*)l, 16, 0, 0);
}

// x: [32][128][3136] f32 -> xt: [32][3136][128] bf16 (NCHW -> NHWC + cvt)
// 64c x 64p tile. Phase 1: float4 reads along p, 8B LDS vector stores.
// Phase 2: 8 scalar LDS reads -> u16x8 16B coalesced global store.
__global__ __launch_bounds__(256) void k_transpose_x(const float* __restrict__ x,
                                                     u16* __restrict__ xt) {
  __shared__ u16 tile[64][68];   // row = c; 136B row stride (8B aligned, conflict-benign)
  const int n  = blockIdx.z;
  const int p0 = blockIdx.x * 64;
  const int c0 = blockIdx.y * 64;
  const int t  = threadIdx.x;

  const float* xp = x + (size_t)n * CIN * HWP + (size_t)c0 * HWP + p0;
  const int pl = (t & 15) * 4;   // pixel offset within tile
  const int cr = t >> 4;         // channel row 0..15 (+16j)
#pragma unroll
  for (int j = 0; j < 4; ++j) {
    int c = cr + j * 16;
    f32x4 v = *(const f32x4*)&xp[(size_t)c * HWP + pl];
    u16x4 h;
    h[0] = f2b(v[0]); h[1] = f2b(v[1]); h[2] = f2b(v[2]); h[3] = f2b(v[3]);
    *(u16x4*)&tile[c][pl] = h;
  }
  __syncthreads();
  u16* xo = xt + (size_t)n * HWP * CIN + (size_t)p0 * CIN + c0;
  const int ch = (t & 7) * 8;    // channel chunk
  const int pr = t >> 3;         // pixel row 0..31 (+32j)
#pragma unroll
  for (int j = 0; j < 2; ++j) {
    int p = pr + j * 32;
    u16x8 o;
#pragma unroll
    for (int i = 0; i < 8; ++i) o[i] = tile[ch + i][p];
    *(u16x8*)&xo[(size_t)p * CIN + ch] = o;   // lanes 0..7 -> 128B contiguous
  }
}

// w: [256][128][3][3] f32 -> Wt: [256][1152] bf16 with k = (kh*3+kw)*128 + ci
// Also zero the 128-element bf16 pad page zb.
__global__ __launch_bounds__(256) void k_transform_w(const float* __restrict__ w,
                                                     u16* __restrict__ Wt,
                                                     u16* __restrict__ zb) {
  int o = blockIdx.x * 256 + threadIdx.x;
  if (o < COUT * KTOT) {
    int co  = o / KTOT;
    int rem = o - co * KTOT;
    int kk  = rem >> 7;      // (kh*3+kw)
    int ci  = rem & 127;
    int kh  = kk / 3;
    int kw  = kk - kh * 3;
    Wt[o] = f2b(w[(((size_t)co * CIN + ci) * 3 + kh) * 3 + kw]);
  }
  if (blockIdx.x == 0 && threadIdx.x < 128) zb[threadIdx.x] = 0;
}

// Implicit-GEMM conv. Grid (784, 2), block 256 (4 waves).
// 128x128 tile, BK=64, 18 K-iters, XOR piece-swizzled LDS (conflict-free b128 reads).
__global__ __launch_bounds__(256, 4) void k_conv_gemm(
    const u16* __restrict__ xt, const u16* __restrict__ Wt,
    const u16* __restrict__ zb, const float* __restrict__ bias,
    float* __restrict__ out) {
  __shared__ u16 lW[128 * 64];   // 16 KB, row-major 128B rows, pieces swizzled
  __shared__ u16 lX[128 * 64];   // 16 KB

  const int tid  = threadIdx.x;
  const int wave = tid >> 6;
  const int lane = tid & 63;
  const int m0   = blockIdx.x * 128;
  const int co0  = blockIdx.y * 128;

  const int wrow = (wave >> 1) * 64;   // co offset of this wave's 64x64
  const int wcol = (wave & 1) * 64;    // m offset

  // staging lane map: LDS slot = (row rsub, piece-slot lane&7); global piece ps = slot ^ row
  const int rsub = lane >> 3;                 // 0..7
  const int pso  = (((lane & 7) ^ rsub)) * 8; // swizzled global k-offset (elements)

  int soh[4], sow[4], sbase[4];
#pragma unroll
  for (int c = 0; c < 4; ++c) {
    int chunk = wave * 4 + c;
    int m = m0 + chunk * 8 + rsub;
    int n = m / HWP;
    int s = m - n * HWP;
    int oh = s / WWD;
    int ow = s - oh * WWD;
    soh[c] = oh; sow[c] = ow;
    sbase[c] = n * HWP + oh * WWD + ow;
  }

  f32x4 acc[4][4];
#pragma unroll
  for (int i = 0; i < 4; ++i)
#pragma unroll
    for (int j = 0; j < 4; ++j) acc[i][j] = (f32x4){0.f, 0.f, 0.f, 0.f};

  const int r  = lane & 15;
  const int q  = lane >> 4;
  const int r7 = r & 7;

  for (int kt = 0; kt < 18; ++kt) {
    const int ksp = kt >> 1;              // 0..8 = kh*3+kw
    const int kh  = ksp / 3;
    const int kw  = ksp - kh * 3;
    const int ci0 = (kt & 1) << 6;        // 0 or 64
    const int kg  = kt << 6;

    __syncthreads();   // all waves done reading LDS from previous iter
#pragma unroll
    for (int c = 0; c < 4; ++c) {         // stage W tile (16 KB)
      int rowW = wave * 32 + c * 8;
      const u16* g = Wt + (size_t)(co0 + rowW + rsub) * KTOT + kg + pso;
      load_lds16(g, &lW[rowW * 64]);
    }
#pragma unroll
    for (int c = 0; c < 4; ++c) {         // stage X tile (16 KB), halo -> zero page
      int ih = soh[c] + kh - 1;
      int iw = sow[c] + kw - 1;
      bool valid = ((unsigned)ih < HH) && ((unsigned)iw < WWD);
      const u16* g = valid
          ? xt + (size_t)(sbase[c] + (kh - 1) * WWD + (kw - 1)) * CIN + ci0 + pso
          : zb + pso;
      load_lds16(g, &lX[(wave * 32 + c * 8) * 64]);
    }
    __syncthreads();   // staged data visible

#pragma unroll
    for (int kk = 0; kk < 2; ++kk) {
      bf16x8 a[4], b[4];
      const int sw = ((kk * 4 + q) ^ r7) * 8;   // swizzled segment offset (elements)
#pragma unroll
      for (int ti = 0; ti < 4; ++ti)
        a[ti] = *(const bf16x8*)(&lW[(wrow + ti * 16 + r) * 64 + sw]);
#pragma unroll
      for (int tj = 0; tj < 4; ++tj)
        b[tj] = *(const bf16x8*)(&lX[(wcol + tj * 16 + r) * 64 + sw]);
#pragma unroll
      for (int ti = 0; ti < 4; ++ti)
#pragma unroll
        for (int tj = 0; tj < 4; ++tj)
          acc[ti][tj] =
              __builtin_amdgcn_mfma_f32_16x16x32_bf16(a[ti], b[tj], acc[ti][tj], 0, 0, 0);
    }
  }

  // Epilogue: C/D layout col=lane&15 (m), row=q*4+reg (co). Add bias, store f32.
#pragma unroll
  for (int tj = 0; tj < 4; ++tj) {
    int m = m0 + wcol + tj * 16 + r;
    int n = m / HWP;
    int s = m - n * HWP;
#pragma unroll
    for (int ti = 0; ti < 4; ++ti) {
      f32x4 v = acc[ti][tj];
#pragma unroll
      for (int e = 0; e < 4; ++e) {
        int co = co0 + wrow + ti * 16 + q * 4 + e;
        out[((size_t)n * COUT + co) * HWP + s] = v[e] + bias[co];
      }
    }
  }
}

extern "C" void kernel_launch(void* const* d_in, const int* in_sizes, int n_in,
                              void* d_out, int out_size, void* d_ws, size_t ws_size,
                              hipStream_t stream) {
  const float* x    = (const float*)d_in[0];
  const float* w    = (const float*)d_in[1];
  const float* bias = (const float*)d_in[2];
  float* out        = (float*)d_out;

  u16* xt = (u16*)d_ws;                       // 12,845,056 bf16 = 25.7 MB
  u16* Wt = xt + (size_t)NB * HWP * CIN;      // 294,912 bf16
  u16* zb = Wt + (size_t)COUT * KTOT;         // 128 bf16 zero page

  k_transform_w<<<dim3(1152), dim3(256), 0, stream>>>(w, Wt, zb);
  k_transpose_x<<<dim3(49, 2, 32), dim3(256), 0, stream>>>(x, xt);
  k_conv_gemm<<<dim3(784, 2), dim3(256), 0, stream>>>(xt, Wt, zb, bias, out);
}